// Round 12
// baseline (298.289 us; speedup 1.0000x reference)
//
#include <hip/hip_runtime.h>
#include <hip/hip_bf16.h>
#include <hip/hip_fp16.h>
#include <stdint.h>

#define N_NODES 50000
#define E_EDGES 800000
#define NBKT 196           // ceil(50000/256) buckets of 256 nodes
#define PBUF 6144          // build_csr LDS perm buffer (records)

typedef short s16x8 __attribute__((ext_vector_type(8)));
typedef _Float16 f16x8 __attribute__((ext_vector_type(8)));
typedef float f32x4 __attribute__((ext_vector_type(4)));

__device__ __forceinline__ unsigned short f2h_bits(float f) {
    return __half_as_ushort(__float2half(f));
}
__device__ __forceinline__ float h2f(unsigned short u) {
    __half h = *reinterpret_cast<const __half*>(&u);
    return __half2float(h);
}
__device__ __forceinline__ float2 h2f2(unsigned int u) {
    __half2 h = *reinterpret_cast<const __half2*>(&u);
    return __half22float2(h);
}

// ---------------- Stage 1: bucket histogram + fused x->fp16 convert -------
__global__ __launch_bounds__(256) void khist_conv(
    const int* __restrict__ dst, int* __restrict__ gbcnt,
    const float* __restrict__ x, unsigned short* __restrict__ xh) {
    __shared__ int bcnt[NBKT];
    int t = threadIdx.x;
    for (int i = t; i < NBKT; i += 256) bcnt[i] = 0;
    __syncthreads();
    int gid = blockIdx.x * 256 + t;
    const int STRIDE = 256 * 256;
    const float4* xv = (const float4*)x;
    for (int e = gid; e < E_EDGES; e += STRIDE) {
        atomicAdd(&bcnt[dst[e] >> 8], 1);
        float4 a = xv[(size_t)2 * e];
        float4 b = xv[(size_t)2 * e + 1];
        s16x8 h;
        h[0] = (short)f2h_bits(a.x); h[1] = (short)f2h_bits(a.y);
        h[2] = (short)f2h_bits(a.z); h[3] = (short)f2h_bits(a.w);
        h[4] = (short)f2h_bits(b.x); h[5] = (short)f2h_bits(b.y);
        h[6] = (short)f2h_bits(b.z); h[7] = (short)f2h_bits(b.w);
        *(s16x8*)(xh + (size_t)e * 8) = h;
    }
    __syncthreads();
    for (int i = t; i < NBKT; i += 256) atomicAdd(&gbcnt[i], bcnt[i]);
}

// ---------------- Stage 2: scan bucket counts -> bases + cursors ----------
__global__ void scan_bkt(const int* __restrict__ gbcnt, int* __restrict__ bscan,
                         int* __restrict__ gcur) {
    __shared__ int wsum[4];
    int t = threadIdx.x, lane = t & 63, wid = t >> 6;
    int v = (t < NBKT) ? gbcnt[t] : 0;
    int x = v;
#pragma unroll
    for (int off = 1; off < 64; off <<= 1) {
        int tt = __shfl_up(x, off);
        if (lane >= off) x += tt;
    }
    if (lane == 63) wsum[wid] = x;
    __syncthreads();
    if (t == 0) {
        int s = 0;
#pragma unroll
        for (int i = 0; i < 4; i++) { int tmp = wsum[i]; wsum[i] = s; s += tmp; }
    }
    __syncthreads();
    int excl = x - v + wsum[wid];
    if (t <= NBKT) bscan[t] = excl;    // bscan[NBKT] == E
    if (t < NBKT) gcur[t] = excl;
}

// ---------------- Stage 3: LDS multisplit into bucket-major pool ----------
__global__ __launch_bounds__(256) void bin_pass(
    const int* __restrict__ src, const int* __restrict__ dst,
    int* __restrict__ gcur, unsigned int* __restrict__ pool) {
    __shared__ unsigned int lbuf[NBKT][64];
    __shared__ int lcnt[NBKT];
    __shared__ int lbase[NBKT];
    int tid = threadIdx.x;
    for (int i = tid; i < NBKT; i += 256) lcnt[i] = 0;
    __syncthreads();
    const int EPG = (E_EDGES + gridDim.x - 1) / gridDim.x;
    int e0 = blockIdx.x * EPG;
    int e1 = e0 + EPG; if (e1 > E_EDGES) e1 = E_EDGES;
    for (int wbase = e0; wbase < e1; wbase += 2048) {
        int wend = wbase + 2048; if (wend > e1) wend = e1;
        int d8[8], s8[8], n8 = 0;
        {
            int e = wbase + tid;
#pragma unroll
            for (int k = 0; k < 8; k++, e += 256)
                if (e < wend) { d8[n8] = dst[e]; s8[n8] = src[e]; n8++; }
        }
        for (int k = 0; k < n8; k++) {
            int d = d8[k];
            unsigned int rec = (unsigned int)(s8[k] & 0xFFFF) |
                               ((unsigned int)(d & 255) << 16);
            int b = d >> 8;
            int slot = atomicAdd(&lcnt[b], 1);
            if (slot < 64) lbuf[b][slot] = rec;
            else pool[atomicAdd(&gcur[b], 1)] = rec;
        }
        __syncthreads();
        if (tid < NBKT) {
            int c = lcnt[tid]; if (c > 64) c = 64;
            int lines = c >> 5;
            if (lines) lbase[tid] = atomicAdd(&gcur[tid], lines * 32);
        }
        __syncthreads();
        {
            int wid = tid >> 6, lane = tid & 63;
            for (int b = wid * 49; b < (wid + 1) * 49; b++) {
                int c = lcnt[b]; if (c > 64) c = 64;
                int lines = c >> 5, rem = c & 31;
                for (int l = 0; l < lines; l++)
                    if (lane < 32)
                        pool[lbase[b] + l * 32 + lane] = lbuf[b][l * 32 + lane];
                if (lines && lane < rem) lbuf[b][lane] = lbuf[b][lines * 32 + lane];
                if (lane == 0) lcnt[b] = rem;
            }
        }
        __syncthreads();
    }
    if (tid < NBKT) {
        int c = lcnt[tid]; if (c > 64) c = 64;
        if (c) lbase[tid] = atomicAdd(&gcur[tid], c);
    }
    __syncthreads();
    {
        int wid = tid >> 6, lane = tid & 63;
        for (int b = wid * 49; b < (wid + 1) * 49; b++) {
            int c = lcnt[b]; if (c > 64) c = 64;
            if (lane < c) pool[lbase[b] + lane] = lbuf[b][lane];
        }
    }
}

// ---------------- Stage 4: per-bucket CSR finalize -------------------------
__global__ __launch_bounds__(256) void build_csr(
    const unsigned int* __restrict__ pool, const int* __restrict__ bscan,
    int* __restrict__ rowptr, unsigned short* __restrict__ perm) {
    __shared__ int ncnt[256];
    __shared__ int ncur[256];
    __shared__ int wsum[4];
    __shared__ unsigned short pbuf[PBUF];
    int b = blockIdx.x, t = threadIdx.x;
    int base = bscan[b], K = bscan[b + 1] - base;
    ncnt[t] = 0;
    __syncthreads();
    for (int i = t; i < K; i += 256)
        atomicAdd(&ncnt[(pool[base + i] >> 16) & 255], 1);
    __syncthreads();
    int lane = t & 63, wid = t >> 6;
    int v = ncnt[t], x = v;
#pragma unroll
    for (int off = 1; off < 64; off <<= 1) {
        int tt = __shfl_up(x, off);
        if (lane >= off) x += tt;
    }
    if (lane == 63) wsum[wid] = x;
    __syncthreads();
    if (t == 0) {
        int s = 0;
#pragma unroll
        for (int i = 0; i < 4; i++) { int tmp = wsum[i]; wsum[i] = s; s += tmp; }
    }
    __syncthreads();
    int excl = x - v + wsum[wid];
    int node = b * 256 + t;
    if (node <= N_NODES) rowptr[node] = base + excl;
    ncur[t] = excl;
    __syncthreads();
    for (int i = t; i < K; i += 256) {
        unsigned int rec = pool[base + i];
        int nl = (rec >> 16) & 255;
        int pos = atomicAdd(&ncur[nl], 1);
        if (pos < PBUF) pbuf[pos] = (unsigned short)rec;
        else perm[base + pos] = (unsigned short)rec;
    }
    __syncthreads();
    int KK = K < PBUF ? K : PBUF;
    for (int i = t; i < KK; i += 256) perm[base + i] = pbuf[i];
}

// ---- Weight prep: fp16 (single plane) ----
__device__ __forceinline__ void prep_one(const float* __restrict__ W,
                                         unsigned short* __restrict__ Whi,
                                         int K, int F, int Fpad, int i) {
    int S = K / 32, T = Fpad / 16;
    int total = T * S * 64;
    if (i >= total) return;
    int lane = i & 63;
    int s = (i >> 6) % S;
    int t = (i >> 6) / S;
    int col = t * 16 + (lane & 15);
    int k0 = s * 32 + (lane >> 4) * 8;
    s16x8 vh;
#pragma unroll
    for (int j = 0; j < 8; j++) {
        float w = (col < F) ? W[(size_t)(k0 + j) * F + col] : 0.f;
        vh[j] = (short)f2h_bits(w);
    }
    *(s16x8*)(Whi + (size_t)i * 8) = vh;
}

__global__ void prep_all(const float* W1, const float* W2, const float* W3,
                         const float* W4, const float* Wl,
                         unsigned short* W1h, unsigned short* W2h,
                         unsigned short* W3h, unsigned short* W4h,
                         unsigned short* Wlh) {
    int b = blockIdx.x, t = threadIdx.x;
    if (b < 8)       prep_one(W1, W1h, 128, 128, 128, b * 256 + t);
    else if (b < 16) prep_one(W2, W2h, 128, 128, 128, (b - 8) * 256 + t);
    else if (b < 32) prep_one(W3, W3h, 128, 256, 256, (b - 16) * 256 + t);
    else if (b < 64) prep_one(W4, W4h, 256, 256, 256, (b - 32) * 256 + t);
    else             prep_one(Wl, Wlh, 256, 40, 64, (b - 64) * 256 + t);
}

// ===================== Fused gather + MLP kernels ==========================
// 256 threads = 4 waves, 32 rows per block. Phase A: each wave gathers 8
// consecutive nodes (R11 uint4 form: 16-lane quarter reads one 256B row)
// and stores the summed fp16 row directly into LDS in the XOR-swizzled
// MFMA-A layout (lanes 0-15 each hold exactly one 16B granule). One
// __syncthreads, then the MLP stages consume A from LDS. No hFh relay
// buffer, no device-wide gather->MLP barrier.

__device__ __forceinline__ void lds_store_h(unsigned short* lds, int C,
                                            int row, int col, unsigned short v) {
    int cb = col >> 3, e = col & 7;
    lds[row * C + (((cb ^ row) & (C / 8 - 1)) << 3) + e] = v;
}
__device__ __forceinline__ f16x8 lds_load_frag(const unsigned short* lds, int C,
                                               int row, int cb) {
    return *(const f16x8*)(lds + row * C + (((cb ^ row) & (C / 8 - 1)) << 3));
}

// Gather 8 nodes (this wave's share of the block's 32) into Albuf[32][128].
__device__ __forceinline__ void gather_to_lds(
    const unsigned short* __restrict__ feat,
    const int* __restrict__ rowptr,
    const unsigned short* __restrict__ perm,
    unsigned short* Albuf, int row0, int wave, int lane) {
    int sub = lane >> 4, c4 = lane & 15;
    const uint4* fv = (const uint4*)feat;
#pragma unroll 1
    for (int i = 0; i < 8; i++) {
        int lrow = wave * 8 + i;
        int node = row0 + lrow;
        float acc[8];
        if (node < N_NODES) {
            uint4 sv = fv[(size_t)node * 16 + c4];   // self term (sub==0 only)
            float2 a0 = h2f2(sv.x), a1 = h2f2(sv.y), a2 = h2f2(sv.z), a3 = h2f2(sv.w);
            float m = (sub == 0) ? 1.f : 0.f;
            acc[0] = m * a0.x; acc[1] = m * a0.y;
            acc[2] = m * a1.x; acc[3] = m * a1.y;
            acc[4] = m * a2.x; acc[5] = m * a2.y;
            acc[6] = m * a3.x; acc[7] = m * a3.y;
            int beg = rowptr[node], end = rowptr[node + 1];
            for (int base = beg; base < end; base += 64) {
                int cnt = end - base; if (cnt > 64) cnt = 64;
                int pv = (base + lane < end) ? (int)perm[base + lane] : 0;
                int j = 0;
                for (; j + 15 < cnt; j += 16) {
                    int s0 = __shfl(pv, j + sub);
                    int s1 = __shfl(pv, j + 4 + sub);
                    int s2 = __shfl(pv, j + 8 + sub);
                    int s3 = __shfl(pv, j + 12 + sub);
                    uint4 u0 = fv[(size_t)s0 * 16 + c4];
                    uint4 u1 = fv[(size_t)s1 * 16 + c4];
                    uint4 u2 = fv[(size_t)s2 * 16 + c4];
                    uint4 u3 = fv[(size_t)s3 * 16 + c4];
#pragma unroll
                    for (int k = 0; k < 4; k++) {
                        uint4 u = k == 0 ? u0 : (k == 1 ? u1 : (k == 2 ? u2 : u3));
                        float2 b0 = h2f2(u.x), b1 = h2f2(u.y), b2 = h2f2(u.z), b3 = h2f2(u.w);
                        acc[0] += b0.x; acc[1] += b0.y;
                        acc[2] += b1.x; acc[3] += b1.y;
                        acc[4] += b2.x; acc[5] += b2.y;
                        acc[6] += b3.x; acc[7] += b3.y;
                    }
                }
                for (; j + 3 < cnt; j += 4) {
                    int s = __shfl(pv, j + sub);
                    uint4 u = fv[(size_t)s * 16 + c4];
                    float2 b0 = h2f2(u.x), b1 = h2f2(u.y), b2 = h2f2(u.z), b3 = h2f2(u.w);
                    acc[0] += b0.x; acc[1] += b0.y;
                    acc[2] += b1.x; acc[3] += b1.y;
                    acc[4] += b2.x; acc[5] += b2.y;
                    acc[6] += b3.x; acc[7] += b3.y;
                }
                if (j < cnt) {
                    int ix = j + sub;
                    bool ok = ix < cnt;
                    int s = __shfl(pv, ok ? ix : j);
                    uint4 u = fv[(size_t)s * 16 + c4];
                    float m2 = ok ? 1.f : 0.f;
                    float2 b0 = h2f2(u.x), b1 = h2f2(u.y), b2 = h2f2(u.z), b3 = h2f2(u.w);
                    acc[0] += m2 * b0.x; acc[1] += m2 * b0.y;
                    acc[2] += m2 * b1.x; acc[3] += m2 * b1.y;
                    acc[4] += m2 * b2.x; acc[5] += m2 * b2.y;
                    acc[6] += m2 * b3.x; acc[7] += m2 * b3.y;
                }
            }
#pragma unroll
            for (int k = 0; k < 8; k++) {
                acc[k] += __shfl_xor(acc[k], 16);
                acc[k] += __shfl_xor(acc[k], 32);
            }
        } else {
#pragma unroll
            for (int k = 0; k < 8; k++) acc[k] = 0.f;
        }
        if (sub == 0) {
            uint4 o;
            o.x = (unsigned int)f2h_bits(acc[0]) | ((unsigned int)f2h_bits(acc[1]) << 16);
            o.y = (unsigned int)f2h_bits(acc[2]) | ((unsigned int)f2h_bits(acc[3]) << 16);
            o.z = (unsigned int)f2h_bits(acc[4]) | ((unsigned int)f2h_bits(acc[5]) << 16);
            o.w = (unsigned int)f2h_bits(acc[6]) | ((unsigned int)f2h_bits(acc[7]) << 16);
            // store granule c4 of row lrow at swizzled granule slot
            ((uint4*)(Albuf + lrow * 128))[(c4 ^ lrow) & 15] = o;
        }
    }
}

// ---- fused_layer1: gather(xh) -> A[LDS]; h1 = relu(A W1+b1)[LDS];
//      out = relu(h1 W2 + b2) -> xh2 (fp16, [N,128])
__global__ __launch_bounds__(256) void fused_layer1(
    const unsigned short* __restrict__ feat,  // xh [N,128] fp16
    const int* __restrict__ rowptr, const unsigned short* __restrict__ perm,
    const unsigned short* __restrict__ W1h, const float* __restrict__ b1,
    const unsigned short* __restrict__ W2h, const float* __restrict__ b2,
    unsigned short* __restrict__ out) {       // xh2 [N,128] fp16
    __shared__ unsigned short Albuf[32 * 128]; // 8 KB (swizzled A)
    __shared__ unsigned short h1[32 * 128];    // 8 KB
    const int wave = threadIdx.x >> 6, lane = threadIdx.x & 63;
    const int lm = lane & 15, quad = lane >> 4;
    const int row0 = blockIdx.x * 32;
    bool rv1 = (row0 + 16) < N_NODES;

    gather_to_lds(feat, rowptr, perm, Albuf, row0, wave, lane);
    __syncthreads();

    // ---- stage 1: K=128 (S=4), F=128 (TL=2), A from LDS ----
    {
        f32x4 acc[2][2];
#pragma unroll
        for (int t = 0; t < 2; t++)
#pragma unroll
            for (int r = 0; r < 2; r++) {
                f32x4 z = {0.f, 0.f, 0.f, 0.f};
                acc[t][r] = z;
            }
#pragma unroll
        for (int s = 0; s < 4; s++) {
            f16x8 a0 = lds_load_frag(Albuf, 128, lm, s * 4 + quad);
            f16x8 a1 = lds_load_frag(Albuf, 128, 16 + lm, s * 4 + quad);
#pragma unroll
            for (int t = 0; t < 2; t++) {
                int tg = wave * 2 + t;
                const f16x8 bh = *(const f16x8*)(W1h + (size_t)((tg * 4 + s) * 64 + lane) * 8);
                acc[t][0] = __builtin_amdgcn_mfma_f32_16x16x32_f16(a0, bh, acc[t][0], 0, 0, 0);
                acc[t][1] = __builtin_amdgcn_mfma_f32_16x16x32_f16(a1, bh, acc[t][1], 0, 0, 0);
            }
        }
#pragma unroll
        for (int r = 0; r < 2; r++)
#pragma unroll
            for (int t = 0; t < 2; t++) {
                int col = (wave * 2 + t) * 16 + lm;
                float bv = b1[col];
#pragma unroll
                for (int q = 0; q < 4; q++) {
                    float vv = fmaxf(acc[t][r][q] + bv, 0.f);
                    lds_store_h(h1, 128, r * 16 + quad * 4 + q, col, f2h_bits(vv));
                }
            }
    }
    __syncthreads();

    // ---- stage 2: K=128 (S=4) from LDS(h1), F=128 (TL=2) -> global fp16 ----
    {
        f32x4 acc[2][2];
#pragma unroll
        for (int t = 0; t < 2; t++)
#pragma unroll
            for (int r = 0; r < 2; r++) {
                f32x4 z = {0.f, 0.f, 0.f, 0.f};
                acc[t][r] = z;
            }
#pragma unroll
        for (int s = 0; s < 4; s++) {
            f16x8 a0 = lds_load_frag(h1, 128, lm, s * 4 + quad);
            f16x8 a1 = lds_load_frag(h1, 128, 16 + lm, s * 4 + quad);
#pragma unroll
            for (int t = 0; t < 2; t++) {
                int tg = wave * 2 + t;
                const f16x8 bh = *(const f16x8*)(W2h + (size_t)((tg * 4 + s) * 64 + lane) * 8);
                acc[t][0] = __builtin_amdgcn_mfma_f32_16x16x32_f16(a0, bh, acc[t][0], 0, 0, 0);
                acc[t][1] = __builtin_amdgcn_mfma_f32_16x16x32_f16(a1, bh, acc[t][1], 0, 0, 0);
            }
        }
#pragma unroll
        for (int r = 0; r < 2; r++) {
            if (r == 1 && !rv1) break;
            int orow = row0 + r * 16 + quad * 4;
#pragma unroll
            for (int t = 0; t < 2; t++) {
                int col = (wave * 2 + t) * 16 + lm;
                float bv = b2[col];
#pragma unroll
                for (int q = 0; q < 4; q++) {
                    float vv = fmaxf(acc[t][r][q] + bv, 0.f);
                    out[(size_t)(orow + q) * 128 + col] = f2h_bits(vv);
                }
            }
        }
    }
}

// ---- fused_layer2: gather(xh2) -> A[LDS]; h2 = relu(A W3+b3)[LDS];
//      h2b = relu(h2 W4+b4)[LDS]; out = h2b Wl + bl -> f32 [N,40]
__global__ __launch_bounds__(256) void fused_layer2(
    const unsigned short* __restrict__ feat,  // xh2 [N,128] fp16
    const int* __restrict__ rowptr, const unsigned short* __restrict__ perm,
    const unsigned short* __restrict__ W3h, const float* __restrict__ b3,
    const unsigned short* __restrict__ W4h, const float* __restrict__ b4,
    const unsigned short* __restrict__ Wlh, const float* __restrict__ bl,
    float* __restrict__ out) {                // [N,40] f32
    __shared__ unsigned short Albuf[32 * 128]; // 8 KB
    __shared__ unsigned short h2[32 * 256];    // 16 KB
    __shared__ unsigned short h2b[32 * 256];   // 16 KB
    const int wave = threadIdx.x >> 6, lane = threadIdx.x & 63;
    const int lm = lane & 15, quad = lane >> 4;
    const int row0 = blockIdx.x * 32;
    bool rv1 = (row0 + 16) < N_NODES;

    gather_to_lds(feat, rowptr, perm, Albuf, row0, wave, lane);
    __syncthreads();

    // ---- stage 1: K=128 (S=4), F=256 (TL=4), A from LDS -> h2 ----
    {
        f32x4 acc[4][2];
#pragma unroll
        for (int t = 0; t < 4; t++)
#pragma unroll
            for (int r = 0; r < 2; r++) {
                f32x4 z = {0.f, 0.f, 0.f, 0.f};
                acc[t][r] = z;
            }
#pragma unroll
        for (int s = 0; s < 4; s++) {
            f16x8 a0 = lds_load_frag(Albuf, 128, lm, s * 4 + quad);
            f16x8 a1 = lds_load_frag(Albuf, 128, 16 + lm, s * 4 + quad);
#pragma unroll
            for (int t = 0; t < 4; t++) {
                int tg = wave * 4 + t;
                const f16x8 bh = *(const f16x8*)(W3h + (size_t)((tg * 4 + s) * 64 + lane) * 8);
                acc[t][0] = __builtin_amdgcn_mfma_f32_16x16x32_f16(a0, bh, acc[t][0], 0, 0, 0);
                acc[t][1] = __builtin_amdgcn_mfma_f32_16x16x32_f16(a1, bh, acc[t][1], 0, 0, 0);
            }
        }
#pragma unroll
        for (int r = 0; r < 2; r++)
#pragma unroll
            for (int t = 0; t < 4; t++) {
                int col = (wave * 4 + t) * 16 + lm;
                float bv = b3[col];
#pragma unroll
                for (int q = 0; q < 4; q++) {
                    float vv = fmaxf(acc[t][r][q] + bv, 0.f);
                    lds_store_h(h2, 256, r * 16 + quad * 4 + q, col, f2h_bits(vv));
                }
            }
    }
    __syncthreads();

    // ---- stage 2: K=256 (S=8) from LDS(h2), F=256 (TL=4) -> LDS(h2b) ----
    {
        f32x4 acc[4][2];
#pragma unroll
        for (int t = 0; t < 4; t++)
#pragma unroll
            for (int r = 0; r < 2; r++) {
                f32x4 z = {0.f, 0.f, 0.f, 0.f};
                acc[t][r] = z;
            }
#pragma unroll
        for (int s = 0; s < 8; s++) {
            f16x8 a0 = lds_load_frag(h2, 256, lm, s * 4 + quad);
            f16x8 a1 = lds_load_frag(h2, 256, 16 + lm, s * 4 + quad);
#pragma unroll
            for (int t = 0; t < 4; t++) {
                int tg = wave * 4 + t;
                const f16x8 bh = *(const f16x8*)(W4h + (size_t)((tg * 8 + s) * 64 + lane) * 8);
                acc[t][0] = __builtin_amdgcn_mfma_f32_16x16x32_f16(a0, bh, acc[t][0], 0, 0, 0);
                acc[t][1] = __builtin_amdgcn_mfma_f32_16x16x32_f16(a1, bh, acc[t][1], 0, 0, 0);
            }
        }
        __syncthreads();
#pragma unroll
        for (int r = 0; r < 2; r++)
#pragma unroll
            for (int t = 0; t < 4; t++) {
                int col = (wave * 4 + t) * 16 + lm;
                float bv = b4[col];
#pragma unroll
                for (int q = 0; q < 4; q++) {
                    float vv = fmaxf(acc[t][r][q] + bv, 0.f);
                    lds_store_h(h2b, 256, r * 16 + quad * 4 + q, col, f2h_bits(vv));
                }
            }
    }
    __syncthreads();

    // ---- stage 3: K=256 (S=8) from LDS(h2b), F=64 (TL=1) -> f32 out ----
    {
        f32x4 acc[2];
        {
            f32x4 z = {0.f, 0.f, 0.f, 0.f};
            acc[0] = z; acc[1] = z;
        }
#pragma unroll
        for (int s = 0; s < 8; s++) {
            f16x8 a0 = lds_load_frag(h2b, 256, lm, s * 4 + quad);
            f16x8 a1 = lds_load_frag(h2b, 256, 16 + lm, s * 4 + quad);
            const f16x8 bh = *(const f16x8*)(Wlh + (size_t)((wave * 8 + s) * 64 + lane) * 8);
            acc[0] = __builtin_amdgcn_mfma_f32_16x16x32_f16(a0, bh, acc[0], 0, 0, 0);
            acc[1] = __builtin_amdgcn_mfma_f32_16x16x32_f16(a1, bh, acc[1], 0, 0, 0);
        }
        int col = wave * 16 + lm;
        if (col < 40) {
            float bv = bl[col];
#pragma unroll
            for (int r = 0; r < 2; r++) {
                if (r == 1 && !rv1) break;
                int orow = row0 + r * 16 + quad * 4;
#pragma unroll
                for (int q = 0; q < 4; q++) {
                    out[(size_t)(orow + q) * 40 + col] = acc[r][q] + bv;
                }
            }
        }
    }
}

extern "C" void kernel_launch(void* const* d_in, const int* in_sizes, int n_in,
                              void* d_out, int out_size, void* d_ws, size_t ws_size,
                              hipStream_t stream) {
    const float* x  = (const float*)d_in[0];
    const int* ei   = (const int*)d_in[1];
    const float* W1 = (const float*)d_in[2];
    const float* b1 = (const float*)d_in[3];
    const float* W2 = (const float*)d_in[4];
    const float* b2 = (const float*)d_in[5];
    const float* W3 = (const float*)d_in[6];
    const float* b3 = (const float*)d_in[7];
    const float* W4 = (const float*)d_in[8];
    const float* b4 = (const float*)d_in[9];
    const float* Wl = (const float*)d_in[10];
    const float* bl = (const float*)d_in[11];
    float* out = (float*)d_out;

    const int* src = ei;
    const int* dst = ei + E_EDGES;

    char* ws = (char*)d_ws;
    size_t off = 0;
    // fp16 activation planes
    unsigned short* xh  = (unsigned short*)(ws + off); off += (size_t)N_NODES * 128 * 2; // x fp16
    unsigned short* xh2 = (unsigned short*)(ws + off); off += (size_t)N_NODES * 128 * 2; // h1b fp16
    // weight planes (fp16, single bank)
    unsigned short* W1h = (unsigned short*)(ws + off); off += 16384 * 2;
    unsigned short* W2h = (unsigned short*)(ws + off); off += 16384 * 2;
    unsigned short* W3h = (unsigned short*)(ws + off); off += 32768 * 2;
    unsigned short* W4h = (unsigned short*)(ws + off); off += 65536 * 2;
    unsigned short* Wlh = (unsigned short*)(ws + off); off += 16384 * 2;
    off = (off + 255) & ~(size_t)255;
    // CSR machinery
    unsigned int* pool = (unsigned int*)(ws + off); off += (size_t)E_EDGES * 4;
    unsigned short* perm = (unsigned short*)(ws + off); off += (size_t)E_EDGES * 2;
    off = (off + 255) & ~(size_t)255;
    int* rowptr = (int*)(ws + off); off += (size_t)(N_NODES + 1) * 4;
    int* gbcnt  = (int*)(ws + off); off += 256 * 4;
    int* bscan  = (int*)(ws + off); off += 256 * 4;
    int* gcur   = (int*)(ws + off); off += 256 * 4;
    (void)ws_size; (void)in_sizes; (void)n_in; (void)out_size;

    // ---- CSR build (multisplit) + x->fp16 convert ----
    (void)hipMemsetAsync(gbcnt, 0, 256 * 4, stream);
    khist_conv<<<256, 256, 0, stream>>>(dst, gbcnt, x, xh);
    scan_bkt<<<1, 256, 0, stream>>>(gbcnt, bscan, gcur);
    bin_pass<<<256, 256, 0, stream>>>(src, dst, gcur, pool);
    build_csr<<<NBKT, 256, 0, stream>>>(pool, bscan, rowptr, perm);

    // ---- Weight prep (fp16 single-plane) ----
    prep_all<<<72, 256, 0, stream>>>(W1, W2, W3, W4, Wl,
                                     W1h, W2h, W3h, W4h, Wlh);

    const int rblk = (N_NODES + 31) / 32;               // 1563 blocks, 32 rows each

    // ---- Layer 1 (gather + MLP fused) ----
    fused_layer1<<<rblk, 256, 0, stream>>>(xh, rowptr, perm,
                                           W1h, b1, W2h, b2, xh2);

    // ---- Layer 2 (gather + MLP + final linear fused) ----
    fused_layer2<<<rblk, 256, 0, stream>>>(xh2, rowptr, perm,
                                           W3h, b3, W4h, b4, Wlh, bl, out);
}

// Round 13
// 261.437 us; speedup vs baseline: 1.1410x; 1.1410x over previous
//
#include <hip/hip_runtime.h>
#include <hip/hip_bf16.h>
#include <hip/hip_fp16.h>
#include <stdint.h>

#define N_NODES 50000
#define E_EDGES 800000
#define NBKT 196           // ceil(50000/256) buckets of 256 nodes
#define PBUF 6144          // build_csr LDS perm buffer (records)

typedef short s16x8 __attribute__((ext_vector_type(8)));
typedef _Float16 f16x8 __attribute__((ext_vector_type(8)));
typedef float f32x4 __attribute__((ext_vector_type(4)));

__device__ __forceinline__ unsigned short f2h_bits(float f) {
    return __half_as_ushort(__float2half(f));
}
__device__ __forceinline__ float h2f(unsigned short u) {
    __half h = *reinterpret_cast<const __half*>(&u);
    return __half2float(h);
}
__device__ __forceinline__ float2 h2f2(unsigned int u) {
    __half2 h = *reinterpret_cast<const __half2*>(&u);
    return __half22float2(h);
}

// ---------------- Stage 1: bucket histogram + fused x->fp16 convert -------
__global__ __launch_bounds__(256) void khist_conv(
    const int* __restrict__ dst, int* __restrict__ gbcnt,
    const float* __restrict__ x, unsigned short* __restrict__ xh) {
    __shared__ int bcnt[NBKT];
    int t = threadIdx.x;
    for (int i = t; i < NBKT; i += 256) bcnt[i] = 0;
    __syncthreads();
    int gid = blockIdx.x * 256 + t;
    const int STRIDE = 256 * 256;
    const float4* xv = (const float4*)x;
    for (int e = gid; e < E_EDGES; e += STRIDE) {
        atomicAdd(&bcnt[dst[e] >> 8], 1);
        float4 a = xv[(size_t)2 * e];
        float4 b = xv[(size_t)2 * e + 1];
        s16x8 h;
        h[0] = (short)f2h_bits(a.x); h[1] = (short)f2h_bits(a.y);
        h[2] = (short)f2h_bits(a.z); h[3] = (short)f2h_bits(a.w);
        h[4] = (short)f2h_bits(b.x); h[5] = (short)f2h_bits(b.y);
        h[6] = (short)f2h_bits(b.z); h[7] = (short)f2h_bits(b.w);
        *(s16x8*)(xh + (size_t)e * 8) = h;
    }
    __syncthreads();
    for (int i = t; i < NBKT; i += 256) atomicAdd(&gbcnt[i], bcnt[i]);
}

// ---------------- Stage 2: scan bucket counts -> bases + cursors ----------
__global__ void scan_bkt(const int* __restrict__ gbcnt, int* __restrict__ bscan,
                         int* __restrict__ gcur) {
    __shared__ int wsum[4];
    int t = threadIdx.x, lane = t & 63, wid = t >> 6;
    int v = (t < NBKT) ? gbcnt[t] : 0;
    int x = v;
#pragma unroll
    for (int off = 1; off < 64; off <<= 1) {
        int tt = __shfl_up(x, off);
        if (lane >= off) x += tt;
    }
    if (lane == 63) wsum[wid] = x;
    __syncthreads();
    if (t == 0) {
        int s = 0;
#pragma unroll
        for (int i = 0; i < 4; i++) { int tmp = wsum[i]; wsum[i] = s; s += tmp; }
    }
    __syncthreads();
    int excl = x - v + wsum[wid];
    if (t <= NBKT) bscan[t] = excl;    // bscan[NBKT] == E
    if (t < NBKT) gcur[t] = excl;
}

// ---------------- Stage 3: LDS multisplit into bucket-major pool ----------
__global__ __launch_bounds__(256) void bin_pass(
    const int* __restrict__ src, const int* __restrict__ dst,
    int* __restrict__ gcur, unsigned int* __restrict__ pool) {
    __shared__ unsigned int lbuf[NBKT][64];
    __shared__ int lcnt[NBKT];
    __shared__ int lbase[NBKT];
    int tid = threadIdx.x;
    for (int i = tid; i < NBKT; i += 256) lcnt[i] = 0;
    __syncthreads();
    const int EPG = (E_EDGES + gridDim.x - 1) / gridDim.x;
    int e0 = blockIdx.x * EPG;
    int e1 = e0 + EPG; if (e1 > E_EDGES) e1 = E_EDGES;
    for (int wbase = e0; wbase < e1; wbase += 2048) {
        int wend = wbase + 2048; if (wend > e1) wend = e1;
        int d8[8], s8[8], n8 = 0;
        {
            int e = wbase + tid;
#pragma unroll
            for (int k = 0; k < 8; k++, e += 256)
                if (e < wend) { d8[n8] = dst[e]; s8[n8] = src[e]; n8++; }
        }
        for (int k = 0; k < n8; k++) {
            int d = d8[k];
            unsigned int rec = (unsigned int)(s8[k] & 0xFFFF) |
                               ((unsigned int)(d & 255) << 16);
            int b = d >> 8;
            int slot = atomicAdd(&lcnt[b], 1);
            if (slot < 64) lbuf[b][slot] = rec;
            else pool[atomicAdd(&gcur[b], 1)] = rec;
        }
        __syncthreads();
        if (tid < NBKT) {
            int c = lcnt[tid]; if (c > 64) c = 64;
            int lines = c >> 5;
            if (lines) lbase[tid] = atomicAdd(&gcur[tid], lines * 32);
        }
        __syncthreads();
        {
            int wid = tid >> 6, lane = tid & 63;
            for (int b = wid * 49; b < (wid + 1) * 49; b++) {
                int c = lcnt[b]; if (c > 64) c = 64;
                int lines = c >> 5, rem = c & 31;
                for (int l = 0; l < lines; l++)
                    if (lane < 32)
                        pool[lbase[b] + l * 32 + lane] = lbuf[b][l * 32 + lane];
                if (lines && lane < rem) lbuf[b][lane] = lbuf[b][lines * 32 + lane];
                if (lane == 0) lcnt[b] = rem;
            }
        }
        __syncthreads();
    }
    if (tid < NBKT) {
        int c = lcnt[tid]; if (c > 64) c = 64;
        if (c) lbase[tid] = atomicAdd(&gcur[tid], c);
    }
    __syncthreads();
    {
        int wid = tid >> 6, lane = tid & 63;
        for (int b = wid * 49; b < (wid + 1) * 49; b++) {
            int c = lcnt[b]; if (c > 64) c = 64;
            if (lane < c) pool[lbase[b] + lane] = lbuf[b][lane];
        }
    }
}

// ---------------- Stage 4: per-bucket CSR finalize -------------------------
__global__ __launch_bounds__(256) void build_csr(
    const unsigned int* __restrict__ pool, const int* __restrict__ bscan,
    int* __restrict__ rowptr, unsigned short* __restrict__ perm) {
    __shared__ int ncnt[256];
    __shared__ int ncur[256];
    __shared__ int wsum[4];
    __shared__ unsigned short pbuf[PBUF];
    int b = blockIdx.x, t = threadIdx.x;
    int base = bscan[b], K = bscan[b + 1] - base;
    ncnt[t] = 0;
    __syncthreads();
    for (int i = t; i < K; i += 256)
        atomicAdd(&ncnt[(pool[base + i] >> 16) & 255], 1);
    __syncthreads();
    int lane = t & 63, wid = t >> 6;
    int v = ncnt[t], x = v;
#pragma unroll
    for (int off = 1; off < 64; off <<= 1) {
        int tt = __shfl_up(x, off);
        if (lane >= off) x += tt;
    }
    if (lane == 63) wsum[wid] = x;
    __syncthreads();
    if (t == 0) {
        int s = 0;
#pragma unroll
        for (int i = 0; i < 4; i++) { int tmp = wsum[i]; wsum[i] = s; s += tmp; }
    }
    __syncthreads();
    int excl = x - v + wsum[wid];
    int node = b * 256 + t;
    if (node <= N_NODES) rowptr[node] = base + excl;
    ncur[t] = excl;
    __syncthreads();
    for (int i = t; i < K; i += 256) {
        unsigned int rec = pool[base + i];
        int nl = (rec >> 16) & 255;
        int pos = atomicAdd(&ncur[nl], 1);
        if (pos < PBUF) pbuf[pos] = (unsigned short)rec;
        else perm[base + pos] = (unsigned short)rec;
    }
    __syncthreads();
    int KK = K < PBUF ? K : PBUF;
    for (int i = t; i < KK; i += 256) perm[base + i] = pbuf[i];
}

// ---------------- Aggregation over fp16 rows, fp16 output -----------------
__global__ __launch_bounds__(256) void gather_agg_h(
    const unsigned short* __restrict__ feat,
    const int* __restrict__ rowptr,
    const unsigned short* __restrict__ perm,
    unsigned short* __restrict__ out) {
    int node = (blockIdx.x * 256 + threadIdx.x) >> 6;
    if (node >= N_NODES) return;
    int lane = threadIdx.x & 63;
    const unsigned int* fv = (const unsigned int*)feat;
    float2 acc = h2f2(fv[(size_t)node * 64 + lane]);
    int beg = rowptr[node], end = rowptr[node + 1];
    for (int base = beg; base < end; base += 64) {
        int cnt = end - base; if (cnt > 64) cnt = 64;
        int pv = (base + lane < end) ? (int)perm[base + lane] : 0;
        int j = 0;
        for (; j + 7 < cnt; j += 8) {
            int s0 = __shfl(pv, j);
            int s1 = __shfl(pv, j + 1);
            int s2 = __shfl(pv, j + 2);
            int s3 = __shfl(pv, j + 3);
            int s4 = __shfl(pv, j + 4);
            int s5 = __shfl(pv, j + 5);
            int s6 = __shfl(pv, j + 6);
            int s7 = __shfl(pv, j + 7);
            unsigned int u0 = fv[(size_t)s0 * 64 + lane];
            unsigned int u1 = fv[(size_t)s1 * 64 + lane];
            unsigned int u2 = fv[(size_t)s2 * 64 + lane];
            unsigned int u3 = fv[(size_t)s3 * 64 + lane];
            unsigned int u4 = fv[(size_t)s4 * 64 + lane];
            unsigned int u5 = fv[(size_t)s5 * 64 + lane];
            unsigned int u6 = fv[(size_t)s6 * 64 + lane];
            unsigned int u7 = fv[(size_t)s7 * 64 + lane];
            float2 f0 = h2f2(u0), f1 = h2f2(u1), f2 = h2f2(u2), f3 = h2f2(u3);
            float2 f4 = h2f2(u4), f5 = h2f2(u5), f6 = h2f2(u6), f7 = h2f2(u7);
            acc.x += (f0.x + f1.x) + (f2.x + f3.x);
            acc.y += (f0.y + f1.y) + (f2.y + f3.y);
            acc.x += (f4.x + f5.x) + (f6.x + f7.x);
            acc.y += (f4.y + f5.y) + (f6.y + f7.y);
        }
        for (; j + 1 < cnt; j += 2) {
            int s0 = __shfl(pv, j);
            int s1 = __shfl(pv, j + 1);
            unsigned int u0 = fv[(size_t)s0 * 64 + lane];
            unsigned int u1 = fv[(size_t)s1 * 64 + lane];
            float2 f0 = h2f2(u0), f1 = h2f2(u1);
            acc.x += f0.x + f1.x;
            acc.y += f0.y + f1.y;
        }
        if (j < cnt) {
            int s = __shfl(pv, j);
            float2 f = h2f2(fv[(size_t)s * 64 + lane]);
            acc.x += f.x;
            acc.y += f.y;
        }
    }
    unsigned int o = (unsigned int)f2h_bits(acc.x) | ((unsigned int)f2h_bits(acc.y) << 16);
    ((unsigned int*)out)[(size_t)node * 64 + lane] = o;
}

// ---- Weight prep: fp16 (single plane — weight-lo error ~2e-3 is far below
//      the fp16-intermediate quantization floor ~0.03 that sets absmax) ----
__device__ __forceinline__ void prep_one(const float* __restrict__ W,
                                         unsigned short* __restrict__ Whi,
                                         int K, int F, int Fpad, int i) {
    int S = K / 32, T = Fpad / 16;
    int total = T * S * 64;
    if (i >= total) return;
    int lane = i & 63;
    int s = (i >> 6) % S;
    int t = (i >> 6) / S;
    int col = t * 16 + (lane & 15);
    int k0 = s * 32 + (lane >> 4) * 8;
    s16x8 vh;
#pragma unroll
    for (int j = 0; j < 8; j++) {
        float w = (col < F) ? W[(size_t)(k0 + j) * F + col] : 0.f;
        vh[j] = (short)f2h_bits(w);
    }
    *(s16x8*)(Whi + (size_t)i * 8) = vh;
}

__global__ void prep_all(const float* W1, const float* W2, const float* W3,
                         const float* W4, const float* Wl,
                         unsigned short* W1h, unsigned short* W2h,
                         unsigned short* W3h, unsigned short* W4h,
                         unsigned short* Wlh) {
    int b = blockIdx.x, t = threadIdx.x;
    if (b < 8)       prep_one(W1, W1h, 128, 128, 128, b * 256 + t);
    else if (b < 16) prep_one(W2, W2h, 128, 128, 128, (b - 8) * 256 + t);
    else if (b < 32) prep_one(W3, W3h, 128, 256, 256, (b - 16) * 256 + t);
    else if (b < 64) prep_one(W4, W4h, 256, 256, 256, (b - 32) * 256 + t);
    else             prep_one(Wl, Wlh, 256, 40, 64, (b - 64) * 256 + t);
}

// ===================== Fused MLP kernels (R7 structure, single bank) =======
__device__ __forceinline__ void lds_store_h(unsigned short* lds, int C,
                                            int row, int col, unsigned short v) {
    int cb = col >> 3, e = col & 7;
    lds[row * C + (((cb ^ row) & (C / 8 - 1)) << 3) + e] = v;
}
__device__ __forceinline__ f16x8 lds_load_frag(const unsigned short* lds, int C,
                                               int row, int cb) {
    return *(const f16x8*)(lds + row * C + (((cb ^ row) & (C / 8 - 1)) << 3));
}

// ---- layer1_mlp: h1 = relu(A W1 + b1) [LDS]; out = relu(h1 W2 + b2) -> fp16
__global__ __launch_bounds__(256) void layer1_mlp(
    const unsigned short* __restrict__ A,     // [N,128] fp16
    const unsigned short* __restrict__ W1h, const float* __restrict__ b1,
    const unsigned short* __restrict__ W2h, const float* __restrict__ b2,
    unsigned short* __restrict__ out) {       // [N,128] fp16
    __shared__ unsigned short h1[32 * 128];   // 8 KB
    const int wave = threadIdx.x >> 6, lane = threadIdx.x & 63;
    const int lm = lane & 15, quad = lane >> 4;
    const int row0 = blockIdx.x * 32;
    bool rv1 = (row0 + 16) < N_NODES;         // r=0 always valid

    {
        f16x8 a[2][4];
#pragma unroll
        for (int r = 0; r < 2; r++) {
            int rr = (r == 0 || rv1) ? row0 + r * 16 : row0;
            const unsigned short* ap = A + (size_t)(rr + lm) * 128 + quad * 8;
#pragma unroll
            for (int s = 0; s < 4; s++) a[r][s] = *(const f16x8*)(ap + s * 32);
        }
        f32x4 acc[2][2];
#pragma unroll
        for (int t = 0; t < 2; t++)
#pragma unroll
            for (int r = 0; r < 2; r++) {
                f32x4 z = {0.f, 0.f, 0.f, 0.f};
                acc[t][r] = z;
            }
#pragma unroll
        for (int s = 0; s < 4; s++) {
#pragma unroll
            for (int t = 0; t < 2; t++) {
                int tg = wave * 2 + t;
                const f16x8 bh = *(const f16x8*)(W1h + (size_t)((tg * 4 + s) * 64 + lane) * 8);
#pragma unroll
                for (int r = 0; r < 2; r++)
                    acc[t][r] = __builtin_amdgcn_mfma_f32_16x16x32_f16(a[r][s], bh, acc[t][r], 0, 0, 0);
            }
        }
#pragma unroll
        for (int r = 0; r < 2; r++)
#pragma unroll
            for (int t = 0; t < 2; t++) {
                int col = (wave * 2 + t) * 16 + lm;
                float bv = b1[col];
#pragma unroll
                for (int q = 0; q < 4; q++) {
                    float vv = fmaxf(acc[t][r][q] + bv, 0.f);
                    lds_store_h(h1, 128, r * 16 + quad * 4 + q, col, f2h_bits(vv));
                }
            }
    }
    __syncthreads();

    {
        f32x4 acc[2][2];
#pragma unroll
        for (int t = 0; t < 2; t++)
#pragma unroll
            for (int r = 0; r < 2; r++) {
                f32x4 z = {0.f, 0.f, 0.f, 0.f};
                acc[t][r] = z;
            }
#pragma unroll
        for (int s = 0; s < 4; s++) {
            f16x8 a0 = lds_load_frag(h1, 128, lm, s * 4 + quad);
            f16x8 a1 = lds_load_frag(h1, 128, 16 + lm, s * 4 + quad);
#pragma unroll
            for (int t = 0; t < 2; t++) {
                int tg = wave * 2 + t;
                const f16x8 bh = *(const f16x8*)(W2h + (size_t)((tg * 4 + s) * 64 + lane) * 8);
                acc[t][0] = __builtin_amdgcn_mfma_f32_16x16x32_f16(a0, bh, acc[t][0], 0, 0, 0);
                acc[t][1] = __builtin_amdgcn_mfma_f32_16x16x32_f16(a1, bh, acc[t][1], 0, 0, 0);
            }
        }
#pragma unroll
        for (int r = 0; r < 2; r++) {
            if (r == 1 && !rv1) break;
            int orow = row0 + r * 16 + quad * 4;
#pragma unroll
            for (int t = 0; t < 2; t++) {
                int col = (wave * 2 + t) * 16 + lm;
                float bv = b2[col];
#pragma unroll
                for (int q = 0; q < 4; q++) {
                    float vv = fmaxf(acc[t][r][q] + bv, 0.f);
                    out[(size_t)(orow + q) * 128 + col] = f2h_bits(vv);
                }
            }
        }
    }
}

// ---- layer2_mlp: h2 = relu(A W3 + b3) [LDS]; h2b = relu(h2 W4 + b4) [LDS];
//                  out = h2b Wl + bl -> f32 [N,40]
__global__ __launch_bounds__(256) void layer2_mlp(
    const unsigned short* __restrict__ A,     // [N,128] fp16
    const unsigned short* __restrict__ W3h, const float* __restrict__ b3,
    const unsigned short* __restrict__ W4h, const float* __restrict__ b4,
    const unsigned short* __restrict__ Wlh, const float* __restrict__ bl,
    float* __restrict__ out) {                // [N,40] f32
    __shared__ unsigned short h2[32 * 256];   // 16 KB
    __shared__ unsigned short h2b[32 * 256];  // 16 KB
    const int wave = threadIdx.x >> 6, lane = threadIdx.x & 63;
    const int lm = lane & 15, quad = lane >> 4;
    const int row0 = blockIdx.x * 32;
    bool rv1 = (row0 + 16) < N_NODES;

    {
        f16x8 a[2][4];
#pragma unroll
        for (int r = 0; r < 2; r++) {
            int rr = (r == 0 || rv1) ? row0 + r * 16 : row0;
            const unsigned short* ap = A + (size_t)(rr + lm) * 128 + quad * 8;
#pragma unroll
            for (int s = 0; s < 4; s++) a[r][s] = *(const f16x8*)(ap + s * 32);
        }
        f32x4 acc[4][2];
#pragma unroll
        for (int t = 0; t < 4; t++)
#pragma unroll
            for (int r = 0; r < 2; r++) {
                f32x4 z = {0.f, 0.f, 0.f, 0.f};
                acc[t][r] = z;
            }
#pragma unroll
        for (int s = 0; s < 4; s++) {
#pragma unroll
            for (int t = 0; t < 4; t++) {
                int tg = wave * 4 + t;
                const f16x8 bh = *(const f16x8*)(W3h + (size_t)((tg * 4 + s) * 64 + lane) * 8);
#pragma unroll
                for (int r = 0; r < 2; r++)
                    acc[t][r] = __builtin_amdgcn_mfma_f32_16x16x32_f16(a[r][s], bh, acc[t][r], 0, 0, 0);
            }
        }
#pragma unroll
        for (int r = 0; r < 2; r++)
#pragma unroll
            for (int t = 0; t < 4; t++) {
                int col = (wave * 4 + t) * 16 + lm;
                float bv = b3[col];
#pragma unroll
                for (int q = 0; q < 4; q++) {
                    float vv = fmaxf(acc[t][r][q] + bv, 0.f);
                    lds_store_h(h2, 256, r * 16 + quad * 4 + q, col, f2h_bits(vv));
                }
            }
    }
    __syncthreads();

    {
        f32x4 acc[4][2];
#pragma unroll
        for (int t = 0; t < 4; t++)
#pragma unroll
            for (int r = 0; r < 2; r++) {
                f32x4 z = {0.f, 0.f, 0.f, 0.f};
                acc[t][r] = z;
            }
#pragma unroll
        for (int s = 0; s < 8; s++) {
            f16x8 a0 = lds_load_frag(h2, 256, lm, s * 4 + quad);
            f16x8 a1 = lds_load_frag(h2, 256, 16 + lm, s * 4 + quad);
#pragma unroll
            for (int t = 0; t < 4; t++) {
                int tg = wave * 4 + t;
                const f16x8 bh = *(const f16x8*)(W4h + (size_t)((tg * 8 + s) * 64 + lane) * 8);
                acc[t][0] = __builtin_amdgcn_mfma_f32_16x16x32_f16(a0, bh, acc[t][0], 0, 0, 0);
                acc[t][1] = __builtin_amdgcn_mfma_f32_16x16x32_f16(a1, bh, acc[t][1], 0, 0, 0);
            }
        }
        __syncthreads();
#pragma unroll
        for (int r = 0; r < 2; r++)
#pragma unroll
            for (int t = 0; t < 4; t++) {
                int col = (wave * 4 + t) * 16 + lm;
                float bv = b4[col];
#pragma unroll
                for (int q = 0; q < 4; q++) {
                    float vv = fmaxf(acc[t][r][q] + bv, 0.f);
                    lds_store_h(h2b, 256, r * 16 + quad * 4 + q, col, f2h_bits(vv));
                }
            }
    }
    __syncthreads();

    {
        f32x4 acc[2];
        {
            f32x4 z = {0.f, 0.f, 0.f, 0.f};
            acc[0] = z; acc[1] = z;
        }
#pragma unroll
        for (int s = 0; s < 8; s++) {
            f16x8 a0 = lds_load_frag(h2b, 256, lm, s * 4 + quad);
            f16x8 a1 = lds_load_frag(h2b, 256, 16 + lm, s * 4 + quad);
            const f16x8 bh = *(const f16x8*)(Wlh + (size_t)((wave * 8 + s) * 64 + lane) * 8);
            acc[0] = __builtin_amdgcn_mfma_f32_16x16x32_f16(a0, bh, acc[0], 0, 0, 0);
            acc[1] = __builtin_amdgcn_mfma_f32_16x16x32_f16(a1, bh, acc[1], 0, 0, 0);
        }
        int col = wave * 16 + lm;
        if (col < 40) {
            float bv = bl[col];
#pragma unroll
            for (int r = 0; r < 2; r++) {
                if (r == 1 && !rv1) break;
                int orow = row0 + r * 16 + quad * 4;
#pragma unroll
                for (int q = 0; q < 4; q++) {
                    out[(size_t)(orow + q) * 40 + col] = acc[r][q] + bv;
                }
            }
        }
    }
}

extern "C" void kernel_launch(void* const* d_in, const int* in_sizes, int n_in,
                              void* d_out, int out_size, void* d_ws, size_t ws_size,
                              hipStream_t stream) {
    const float* x  = (const float*)d_in[0];
    const int* ei   = (const int*)d_in[1];
    const float* W1 = (const float*)d_in[2];
    const float* b1 = (const float*)d_in[3];
    const float* W2 = (const float*)d_in[4];
    const float* b2 = (const float*)d_in[5];
    const float* W3 = (const float*)d_in[6];
    const float* b3 = (const float*)d_in[7];
    const float* W4 = (const float*)d_in[8];
    const float* b4 = (const float*)d_in[9];
    const float* Wl = (const float*)d_in[10];
    const float* bl = (const float*)d_in[11];
    float* out = (float*)d_out;

    const int* src = ei;
    const int* dst = ei + E_EDGES;

    char* ws = (char*)d_ws;
    size_t off = 0;
    // fp16 activation planes
    unsigned short* xh  = (unsigned short*)(ws + off); off += (size_t)N_NODES * 128 * 2; // x / h1b
    unsigned short* hFh = (unsigned short*)(ws + off); off += (size_t)N_NODES * 128 * 2; // agg out
    // weight planes (fp16, single bank)
    unsigned short* W1h = (unsigned short*)(ws + off); off += 16384 * 2;
    unsigned short* W2h = (unsigned short*)(ws + off); off += 16384 * 2;
    unsigned short* W3h = (unsigned short*)(ws + off); off += 32768 * 2;
    unsigned short* W4h = (unsigned short*)(ws + off); off += 65536 * 2;
    unsigned short* Wlh = (unsigned short*)(ws + off); off += 16384 * 2;
    off = (off + 255) & ~(size_t)255;
    // CSR machinery
    unsigned int* pool = (unsigned int*)(ws + off); off += (size_t)E_EDGES * 4;
    unsigned short* perm = (unsigned short*)(ws + off); off += (size_t)E_EDGES * 2;
    off = (off + 255) & ~(size_t)255;
    int* rowptr = (int*)(ws + off); off += (size_t)(N_NODES + 1) * 4;
    int* gbcnt  = (int*)(ws + off); off += 256 * 4;
    int* bscan  = (int*)(ws + off); off += 256 * 4;
    int* gcur   = (int*)(ws + off); off += 256 * 4;
    (void)ws_size; (void)in_sizes; (void)n_in; (void)out_size;

    // ---- CSR build (multisplit) + x->fp16 convert ----
    (void)hipMemsetAsync(gbcnt, 0, 256 * 4, stream);
    khist_conv<<<256, 256, 0, stream>>>(dst, gbcnt, x, xh);
    scan_bkt<<<1, 256, 0, stream>>>(gbcnt, bscan, gcur);
    bin_pass<<<256, 256, 0, stream>>>(src, dst, gcur, pool);
    build_csr<<<NBKT, 256, 0, stream>>>(pool, bscan, rowptr, perm);

    // ---- Weight prep (fp16 single-plane) ----
    prep_all<<<72, 256, 0, stream>>>(W1, W2, W3, W4, Wl,
                                     W1h, W2h, W3h, W4h, Wlh);

    const int aggBlocks = (N_NODES * 64 + 255) / 256;   // one wave per node
    const int rblk = (N_NODES + 31) / 32;               // 1563 blocks, 32 rows each

    // ---- Layer 1 (fused MLP) ----
    gather_agg_h<<<aggBlocks, 256, 0, stream>>>(xh, rowptr, perm, hFh);
    layer1_mlp<<<rblk, 256, 0, stream>>>(hFh, W1h, b1, W2h, b2, xh);

    // ---- Layer 2 (fused MLP + final linear) ----
    gather_agg_h<<<aggBlocks, 256, 0, stream>>>(xh, rowptr, perm, hFh);
    layer2_mlp<<<rblk, 256, 0, stream>>>(hFh, W3h, b3, W4h, b4, Wlh, bl, out);
}